// Round 1
// baseline (281.882 us; speedup 1.0000x reference)
//
#include <hip/hip_runtime.h>
#include <stdint.h>

// Problem constants (fixed by reference)
#define NN 100000      // nodes
#define NE 1600000     // edges
#define K_DIM 128      // IN_DIM == HID_DIM

// Coarse binning for CSR build
#define BSH 7                                   // 128 nodes per bucket
#define NBKT ((NN + (1 << BSH) - 1) >> BSH)     // 782 buckets
#define EPT 32                                  // edges per thread, pass 1
#define BIN_CHUNK (256 * EPT)                   // 8192 edges per block
#define CAP 4096                                // staging capacity per bucket (exp 2046, sigma 45)
#define PADE 2400000                            // padded edge capacity (<= NE + 7*NN)

typedef unsigned int uint32;
typedef unsigned short ushort16;
typedef __attribute__((ext_vector_type(8))) short bf16x8;
typedef __attribute__((ext_vector_type(4))) float f32x4;

__device__ __forceinline__ ushort16 f2bf(float f) {
    uint32 u = __float_as_uint(f);
    u += 0x7fffu + ((u >> 16) & 1u);   // round-to-nearest-even
    return (ushort16)(u >> 16);
}
__device__ __forceinline__ float bf_lo(uint32 u) { return __uint_as_float(u << 16); }
__device__ __forceinline__ float bf_hi(uint32 u) { return __uint_as_float(u & 0xffff0000u); }

// Load an 8-bf16 MFMA fragment from LDS as 2x ds_read_b64 (8B-aligned, LDA=132)
__device__ __forceinline__ bf16x8 ld_frag8(const ushort16* p) {
    uint2 lo = *(const uint2*)p;
    uint2 hi = *(const uint2*)(p + 4);
    union { uint32 u[4]; bf16x8 v; } x;
    x.u[0] = lo.x; x.u[1] = lo.y; x.u[2] = hi.x; x.u[3] = hi.y;
    return x.v;
}

// ---------------------------------------------------------------------------
// CSR build, all-binned: pass1 fixed-stride bucket scatter ->
// per-bucket degree count (LDS atomics) -> tiny bucket scan ->
// pass2 local scan + fine scatter + pad fill. No global random atomics.
// ---------------------------------------------------------------------------

// Pass 1: bin (src,dst) pairs into fixed-stride coarse buckets (write-combining).
__global__ __launch_bounds__(256) void bin_pass1_kernel(
        const int* __restrict__ ei, int* __restrict__ gcursor,
        uint2* __restrict__ staging) {
    __shared__ int hist[NBKT];
    __shared__ int base[NBKT];
    int tid = threadIdx.x;
    int e0 = blockIdx.x * BIN_CHUNK;

    for (int i = tid; i < NBKT; i += 256) hist[i] = 0;
    __syncthreads();

    #pragma unroll
    for (int k = 0; k < EPT; k++) {
        int e = e0 + k * 256 + tid;
        if (e < NE) {
            int d = ei[NE + e];
            atomicAdd(&hist[d >> BSH], 1);
        }
    }
    __syncthreads();

    for (int i = tid; i < NBKT; i += 256) {
        int c = hist[i];
        base[i] = c ? atomicAdd(&gcursor[i], c) : 0;
        hist[i] = 0;
    }
    __syncthreads();

    #pragma unroll
    for (int k = 0; k < EPT; k++) {
        int e = e0 + k * 256 + tid;
        if (e < NE) {
            int s = ei[e];
            int d = ei[NE + e];
            int b = d >> BSH;
            int off = atomicAdd(&hist[b], 1);
            staging[(size_t)b * CAP + base[b] + off] = make_uint2((uint32)s, (uint32)d);
        }
    }
}

// Per-bucket degree count via LDS atomics; writes deg + dis coalesced and
// the bucket's padded-degree total.
__global__ __launch_bounds__(256) void deg_bucket_kernel(
        const uint2* __restrict__ staging, const int* __restrict__ gcursor,
        int* __restrict__ deg, float* __restrict__ dis, int* __restrict__ bucket_tot) {
    __shared__ int cnt[1 << BSH];
    __shared__ int red[1 << BSH];
    int b = blockIdx.x;
    int node0 = b << BSH;
    int tid = threadIdx.x;
    int n_edges = gcursor[b];

    if (tid < (1 << BSH)) cnt[tid] = 0;
    __syncthreads();

    for (int i = tid; i < n_edges; i += 256) {
        uint2 p = staging[(size_t)b * CAP + i];
        atomicAdd(&cnt[p.y & ((1 << BSH) - 1)], 1);
    }
    __syncthreads();

    if (tid < (1 << BSH)) {
        int node = node0 + tid;
        int c = cnt[tid];
        if (node < NN) {
            deg[node] = c;
            dis[node] = (c > 0) ? rsqrtf((float)c) : 0.0f;
            red[tid] = (c + 7) & ~7;
        } else {
            red[tid] = 0;
        }
    }
    __syncthreads();
    for (int off = (1 << BSH) / 2; off > 0; off >>= 1) {
        if (tid < off) red[tid] += red[tid + off];
        __syncthreads();
    }
    if (tid == 0) bucket_tot[b] = red[0];
}

// Exclusive scan over NBKT bucket totals (single block, 1024 threads).
__global__ void bucket_scan_kernel(const int* __restrict__ bucket_tot,
                                   int* __restrict__ bucket_base,
                                   int* __restrict__ row_start) {
    __shared__ int buf[1024];
    int tid = threadIdx.x;
    int v = (tid < NBKT) ? bucket_tot[tid] : 0;
    buf[tid] = v;
    __syncthreads();
    for (int off = 1; off < 1024; off <<= 1) {
        int t = (tid >= off) ? buf[tid - off] : 0;
        __syncthreads();
        buf[tid] += t;
        __syncthreads();
    }
    if (tid < NBKT) bucket_base[tid] = buf[tid] - v;
    if (tid == NBKT - 1) row_start[NN] = buf[tid];   // total padded edges
}

// Pass 2: per bucket: local 128-wide exclusive scan of padded degrees ->
// row_start; LDS cursors; fine scatter into ssrc; pad fill with dummy NN.
__global__ __launch_bounds__(256) void bin_pass2_kernel(
        const uint2* __restrict__ staging, const int* __restrict__ gcursor,
        const int* __restrict__ deg, const int* __restrict__ bucket_base,
        int* __restrict__ row_start, int* __restrict__ ssrc) {
    __shared__ int sb[1 << BSH];     // scan buffer
    __shared__ int cur[1 << BSH];    // write cursors
    __shared__ int pend[1 << BSH];   // padded end
    int b = blockIdx.x;
    int node0 = b << BSH;
    int tid = threadIdx.x;
    int n_edges = gcursor[b];

    int p = 0;
    if (tid < (1 << BSH)) {
        int node = node0 + tid;
        p = (node < NN) ? ((deg[node] + 7) & ~7) : 0;
        sb[tid] = p;
    }
    __syncthreads();
    #pragma unroll
    for (int off = 1; off < (1 << BSH); off <<= 1) {
        int t = (tid >= off && tid < (1 << BSH)) ? sb[tid - off] : 0;
        __syncthreads();
        if (tid < (1 << BSH)) sb[tid] += t;
        __syncthreads();
    }
    if (tid < (1 << BSH)) {
        int rs = bucket_base[b] + sb[tid] - p;   // exclusive
        cur[tid] = rs;
        pend[tid] = rs + p;
        int node = node0 + tid;
        if (node < NN) row_start[node] = rs;
    }
    __syncthreads();

    for (int i = tid; i < n_edges; i += 256) {
        uint2 pr = staging[(size_t)b * CAP + i];
        int off = atomicAdd(&cur[pr.y & ((1 << BSH) - 1)], 1);
        ssrc[off] = (int)pr.x;
    }
    __syncthreads();

    if (tid < (1 << BSH)) {
        int node = node0 + tid;
        if (node < NN) {
            for (int q = cur[tid]; q < pend[tid]; q++) ssrc[q] = NN;   // dummy -> zero row
        }
    }
}

// ---------------------------------------------------------------------------
// MFMA bf16 GEMM: out[M,N] = bf16( (A[M,128] @ W[128,N]) * dis[row] )
// BM=64, full K=128 resident in LDS, one barrier per block.
// ---------------------------------------------------------------------------
template <int N, bool ABF16>
__global__ __launch_bounds__(256) void gemm_mfma_kernel(
        const void* __restrict__ Ap, const float* __restrict__ W,
        const float* __restrict__ dis, ushort16* __restrict__ out, int M) {
    constexpr int BM = 64, K = K_DIM;
    constexpr int LDA = 132;
    constexpr int NT = N / 16;
    constexpr int NLOG = (N == 128) ? 7 : 6;

    __shared__ ushort16 As[BM * LDA];
    __shared__ ushort16 Bt[N * LDA];

    int tid = threadIdx.x;
    int row0 = blockIdx.x * BM;

    if constexpr (!ABF16) {
        const float* A = (const float*)Ap;
        #pragma unroll
        for (int c = 0; c < 8; c++) {
            int idx = c * 1024 + tid * 4;
            int r = idx >> 7, col = idx & 127;
            int ra = row0 + r;
            float4 v = (ra < M) ? *(const float4*)&A[(size_t)ra * K + col]
                                : make_float4(0.f, 0.f, 0.f, 0.f);
            ushort4 bq;
            bq.x = f2bf(v.x); bq.y = f2bf(v.y); bq.z = f2bf(v.z); bq.w = f2bf(v.w);
            *(ushort4*)&As[r * LDA + col] = bq;
        }
    } else {
        const ushort16* A = (const ushort16*)Ap;
        #pragma unroll
        for (int c = 0; c < 4; c++) {
            int idx = c * 2048 + tid * 8;
            int r = idx >> 7, col = idx & 127;
            int ra = row0 + r;
            uint4 v = make_uint4(0u, 0u, 0u, 0u);
            if (ra < M) v = *(const uint4*)&A[(size_t)ra * K + col];
            *(uint2*)&As[r * LDA + col]     = make_uint2(v.x, v.y);
            *(uint2*)&As[r * LDA + col + 4] = make_uint2(v.z, v.w);
        }
    }
    {
        #pragma unroll
        for (int c = 0; c < (K * N) / 1024; c++) {
            int idx = c * 1024 + tid * 4;
            int k = idx >> NLOG, n = idx & (N - 1);
            float4 v = *(const float4*)&W[idx];
            Bt[(n + 0) * LDA + k] = f2bf(v.x);
            Bt[(n + 1) * LDA + k] = f2bf(v.y);
            Bt[(n + 2) * LDA + k] = f2bf(v.z);
            Bt[(n + 3) * LDA + k] = f2bf(v.w);
        }
    }
    __syncthreads();

    int lane = tid & 63;
    int wv = tid >> 6;
    int m0 = wv * 16;
    int ml = lane & 15;
    int quad = lane >> 4;

    f32x4 acc[NT];
    #pragma unroll
    for (int i = 0; i < NT; i++) acc[i] = (f32x4){0.f, 0.f, 0.f, 0.f};

    #pragma unroll
    for (int ks = 0; ks < 4; ks++) {
        int kof = ks * 32 + quad * 8;
        bf16x8 a = ld_frag8(&As[(m0 + ml) * LDA + kof]);
        #pragma unroll
        for (int nt = 0; nt < NT; nt++) {
            bf16x8 bb = ld_frag8(&Bt[(nt * 16 + ml) * LDA + kof]);
            acc[nt] = __builtin_amdgcn_mfma_f32_16x16x32_bf16(a, bb, acc[nt], 0, 0, 0);
        }
    }

    #pragma unroll
    for (int r = 0; r < 4; r++) {
        int row = row0 + m0 + quad * 4 + r;
        if (row < M) {
            float s = dis[row];
            #pragma unroll
            for (int nt = 0; nt < NT; nt++)
                out[(size_t)row * N + nt * 16 + ml] = f2bf(acc[nt][r] * s);
        }
    }
}

// ---------------------------------------------------------------------------
// Aggregation layer 1: F=128, bf16 gather -> bf16 out with ReLU.
// One wave per node. dwordx4 gather: lane covers feats (lane&15)*8..+7,
// quad (lane>>4) covers an edge sub-slot => 4 edge-rows per load instr.
// Padded CSR (x8) => uniform batches of 8 edges = 2 dwordx4 loads.
// 2-stage shfl_xor tree combines the 4 quad partial sums.
// ---------------------------------------------------------------------------
__global__ __launch_bounds__(256) void agg128_kernel(
        const ushort16* __restrict__ g, const int* __restrict__ row_start,
        const int* __restrict__ ssrc, const float* __restrict__ dis,
        const float* __restrict__ bias, ushort16* __restrict__ out) {
    int wave = (blockIdx.x * 256 + threadIdx.x) >> 6;
    int lane = threadIdx.x & 63;
    if (wave >= NN) return;

    int beg = row_start[wave];
    int end = row_start[wave + 1];
    float sc = dis[wave];

    int fl = lane & 15;            // feature octet: feats fl*8..fl*8+7
    int q  = lane >> 4;            // edge sub-slot 0..3
    int laneoff = fl * 16;         // byte offset within a 256B row

    float a0 = 0.f, a1 = 0.f, a2 = 0.f, a3 = 0.f;
    float a4 = 0.f, a5 = 0.f, a6 = 0.f, a7 = 0.f;

    const char* gb = (const char*)g;
    for (int e = beg; e < end; e += 8) {
        int idx = ssrc[e + (lane & 7)];
        int s0 = __shfl(idx, q);
        int s1 = __shfl(idx, 4 + q);
        uint4 v0 = *(const uint4*)(gb + (((uint32)s0 << 8) + laneoff));
        uint4 v1 = *(const uint4*)(gb + (((uint32)s1 << 8) + laneoff));
        a0 += bf_lo(v0.x); a1 += bf_hi(v0.x);
        a2 += bf_lo(v0.y); a3 += bf_hi(v0.y);
        a4 += bf_lo(v0.z); a5 += bf_hi(v0.z);
        a6 += bf_lo(v0.w); a7 += bf_hi(v0.w);
        a0 += bf_lo(v1.x); a1 += bf_hi(v1.x);
        a2 += bf_lo(v1.y); a3 += bf_hi(v1.y);
        a4 += bf_lo(v1.z); a5 += bf_hi(v1.z);
        a6 += bf_lo(v1.w); a7 += bf_hi(v1.w);
    }

    // combine the 4 quad partial sums (tree)
    a0 += __shfl_xor(a0, 16); a1 += __shfl_xor(a1, 16);
    a2 += __shfl_xor(a2, 16); a3 += __shfl_xor(a3, 16);
    a4 += __shfl_xor(a4, 16); a5 += __shfl_xor(a5, 16);
    a6 += __shfl_xor(a6, 16); a7 += __shfl_xor(a7, 16);
    a0 += __shfl_xor(a0, 32); a1 += __shfl_xor(a1, 32);
    a2 += __shfl_xor(a2, 32); a3 += __shfl_xor(a3, 32);
    a4 += __shfl_xor(a4, 32); a5 += __shfl_xor(a5, 32);
    a6 += __shfl_xor(a6, 32); a7 += __shfl_xor(a7, 32);

    if (lane < 16) {
        float4 bA = *(const float4*)&bias[fl * 8];
        float4 bB = *(const float4*)&bias[fl * 8 + 4];
        float o0 = fmaxf(sc * a0 + bA.x, 0.f);
        float o1 = fmaxf(sc * a1 + bA.y, 0.f);
        float o2 = fmaxf(sc * a2 + bA.z, 0.f);
        float o3 = fmaxf(sc * a3 + bA.w, 0.f);
        float o4 = fmaxf(sc * a4 + bB.x, 0.f);
        float o5 = fmaxf(sc * a5 + bB.y, 0.f);
        float o6 = fmaxf(sc * a6 + bB.z, 0.f);
        float o7 = fmaxf(sc * a7 + bB.w, 0.f);
        uint4 pk;
        pk.x = ((uint32)f2bf(o1) << 16) | (uint32)f2bf(o0);
        pk.y = ((uint32)f2bf(o3) << 16) | (uint32)f2bf(o2);
        pk.z = ((uint32)f2bf(o5) << 16) | (uint32)f2bf(o4);
        pk.w = ((uint32)f2bf(o7) << 16) | (uint32)f2bf(o6);
        *(uint4*)&out[(size_t)wave * 128 + fl * 8] = pk;
    }
}

// ---------------------------------------------------------------------------
// Aggregation layer 2: F=64, bf16 gather -> f32 out (no activation).
// Half-wave per node, dwordx4 gather: lane covers feats (l2&7)*8..+7,
// group (l2>>3) covers an edge sub-slot => 8 edge-rows per load instr
// (4 per node). 2-stage shfl_xor tree within each half-wave.
// ---------------------------------------------------------------------------
__global__ __launch_bounds__(256) void agg64_kernel(
        const ushort16* __restrict__ g, const int* __restrict__ row_start,
        const int* __restrict__ ssrc, const float* __restrict__ dis,
        const float* __restrict__ bias, float* __restrict__ out) {
    int wave = (blockIdx.x * 256 + threadIdx.x) >> 6;
    int lane = threadIdx.x & 63;
    int half = lane >> 5;
    int l2 = lane & 31;
    int node = wave * 2 + half;          // NN even => both halves valid
    if (node >= NN) return;

    int beg = row_start[node];
    int end = row_start[node + 1];
    float sc = dis[node];

    int fl = l2 & 7;               // feature octet: feats fl*8..fl*8+7
    int q  = l2 >> 3;              // edge sub-slot 0..3
    int laneoff = fl * 16;         // byte offset within a 128B row

    float a0 = 0.f, a1 = 0.f, a2 = 0.f, a3 = 0.f;
    float a4 = 0.f, a5 = 0.f, a6 = 0.f, a7 = 0.f;

    const char* gb = (const char*)g;
    for (int e = beg; e < end; e += 8) {
        int idx = ssrc[e + (l2 & 7)];
        int s0 = __shfl(idx, half * 32 + q);
        int s1 = __shfl(idx, half * 32 + 4 + q);
        uint4 v0 = *(const uint4*)(gb + (((uint32)s0 << 7) + laneoff));
        uint4 v1 = *(const uint4*)(gb + (((uint32)s1 << 7) + laneoff));
        a0 += bf_lo(v0.x); a1 += bf_hi(v0.x);
        a2 += bf_lo(v0.y); a3 += bf_hi(v0.y);
        a4 += bf_lo(v0.z); a5 += bf_hi(v0.z);
        a6 += bf_lo(v0.w); a7 += bf_hi(v0.w);
        a0 += bf_lo(v1.x); a1 += bf_hi(v1.x);
        a2 += bf_lo(v1.y); a3 += bf_hi(v1.y);
        a4 += bf_lo(v1.z); a5 += bf_hi(v1.z);
        a6 += bf_lo(v1.w); a7 += bf_hi(v1.w);
    }

    // combine the 4 sub-slot partial sums (tree), within each half-wave
    a0 += __shfl_xor(a0, 8);  a1 += __shfl_xor(a1, 8);
    a2 += __shfl_xor(a2, 8);  a3 += __shfl_xor(a3, 8);
    a4 += __shfl_xor(a4, 8);  a5 += __shfl_xor(a5, 8);
    a6 += __shfl_xor(a6, 8);  a7 += __shfl_xor(a7, 8);
    a0 += __shfl_xor(a0, 16); a1 += __shfl_xor(a1, 16);
    a2 += __shfl_xor(a2, 16); a3 += __shfl_xor(a3, 16);
    a4 += __shfl_xor(a4, 16); a5 += __shfl_xor(a5, 16);
    a6 += __shfl_xor(a6, 16); a7 += __shfl_xor(a7, 16);

    if (l2 < 8) {
        float4 bA = *(const float4*)&bias[fl * 8];
        float4 bB = *(const float4*)&bias[fl * 8 + 4];
        float4 oA = make_float4(sc * a0 + bA.x, sc * a1 + bA.y,
                                sc * a2 + bA.z, sc * a3 + bA.w);
        float4 oB = make_float4(sc * a4 + bB.x, sc * a5 + bB.y,
                                sc * a6 + bB.z, sc * a7 + bB.w);
        *(float4*)&out[(size_t)node * 64 + fl * 8]     = oA;
        *(float4*)&out[(size_t)node * 64 + fl * 8 + 4] = oB;
    }
}

// ---------------------------------------------------------------------------
// Launch
// ---------------------------------------------------------------------------
extern "C" void kernel_launch(void* const* d_in, const int* in_sizes, int n_in,
                              void* d_out, int out_size, void* d_ws, size_t ws_size,
                              hipStream_t stream) {
    const float* x  = (const float*)d_in[0];
    const int*   ei = (const int*)d_in[1];
    const float* W1 = (const float*)d_in[2];
    const float* b1 = (const float*)d_in[3];
    const float* W2 = (const float*)d_in[4];
    const float* b2 = (const float*)d_in[5];
    float* out = (float*)d_out;

    char* ws = (char*)d_ws;
    size_t off = 0;
    auto alloc = [&](size_t bytes) {
        void* p = ws + off;
        off = (off + bytes + 255) & ~(size_t)255;
        return p;
    };

    int*      deg_i      = (int*)alloc(NN * 4);
    float*    dis        = (float*)alloc(NN * 4);
    int*      row_start  = (int*)alloc((NN + 1) * 4);
    int*      gcursor    = (int*)alloc(NBKT * 4);
    int*      bucket_tot = (int*)alloc(NBKT * 4);
    int*      bucket_bse = (int*)alloc(NBKT * 4);
    int*      ssrc       = (int*)alloc((size_t)PADE * 4);
    ushort16* g1         = (ushort16*)alloc((size_t)(NN + 1) * 128 * 2);  // +zero row
    // staging (25.62 MB) and h (25.6 MB) share one region: staging is dead
    // after bin_pass2 (before gemm128), h written first by agg128.
    char*     big        = (char*)alloc((size_t)NBKT * CAP * 8);
    uint2*    staging    = (uint2*)big;
    ushort16* h          = (ushort16*)big;
    ushort16* g2         = g1;               // alias: g1 dead after agg1

    hipMemsetAsync(gcursor, 0, NBKT * 4, stream);
    hipMemsetAsync((char*)g1 + (size_t)NN * 256, 0, 256, stream);   // g1 zero row

    bin_pass1_kernel<<<(NE + BIN_CHUNK - 1) / BIN_CHUNK, 256, 0, stream>>>(ei, gcursor, staging);
    deg_bucket_kernel<<<NBKT, 256, 0, stream>>>(staging, gcursor, deg_i, dis, bucket_tot);
    bucket_scan_kernel<<<1, 1024, 0, stream>>>(bucket_tot, bucket_bse, row_start);
    bin_pass2_kernel<<<NBKT, 256, 0, stream>>>(staging, gcursor, deg_i, bucket_bse, row_start, ssrc);

    const int GEMM_BLOCKS = (NN + 63) / 64;   // 1563
    gemm_mfma_kernel<128, false><<<GEMM_BLOCKS, 256, 0, stream>>>(x, W1, dis, g1, NN);

    const int AGG_BLOCKS = (NN + 3) / 4;      // 25000 (4 waves/block)
    agg128_kernel<<<AGG_BLOCKS, 256, 0, stream>>>(g1, row_start, ssrc, dis, b1, h);

    hipMemsetAsync((char*)g2 + (size_t)NN * 128, 0, 128, stream);   // g2 zero row (g1 now dead)

    gemm_mfma_kernel<64, true><<<GEMM_BLOCKS, 256, 0, stream>>>(h, W2, dis, g2, NN);

    const int AGG2_BLOCKS = (NN / 2 + 3) / 4; // 12500 (half-wave per node)
    agg64_kernel<<<AGG2_BLOCKS, 256, 0, stream>>>(g2, row_start, ssrc, dis, b2, out);
}

// Round 2
// 275.418 us; speedup vs baseline: 1.0235x; 1.0235x over previous
//
#include <hip/hip_runtime.h>
#include <stdint.h>

// Problem constants (fixed by reference)
#define NN 100000      // nodes
#define NE 1600000     // edges
#define K_DIM 128      // IN_DIM == HID_DIM

// Coarse binning for CSR build
#define BSH 7                                   // 128 nodes per bucket
#define NBKT ((NN + (1 << BSH) - 1) >> BSH)     // 782 buckets
#define EPT 32                                  // edges per thread, pass 1
#define BIN_CHUNK (256 * EPT)                   // 8192 edges per block
#define CAP 4096                                // staging capacity per bucket (exp 2046, sigma 45)
#define PADE 2400000                            // padded edge capacity (<= NE + 7*NN; also >= total+64 slack)

typedef unsigned int uint32;
typedef unsigned short ushort16;
typedef __attribute__((ext_vector_type(8))) short bf16x8;
typedef __attribute__((ext_vector_type(4))) float f32x4;

__device__ __forceinline__ ushort16 f2bf(float f) {
    uint32 u = __float_as_uint(f);
    u += 0x7fffu + ((u >> 16) & 1u);   // round-to-nearest-even
    return (ushort16)(u >> 16);
}
__device__ __forceinline__ float bf_lo(uint32 u) { return __uint_as_float(u << 16); }
__device__ __forceinline__ float bf_hi(uint32 u) { return __uint_as_float(u & 0xffff0000u); }

// Accumulate 8 bf16 pairs from a uint4 into a0..a7
#define ACC8(v) do { \
    a0 += bf_lo((v).x); a1 += bf_hi((v).x); \
    a2 += bf_lo((v).y); a3 += bf_hi((v).y); \
    a4 += bf_lo((v).z); a5 += bf_hi((v).z); \
    a6 += bf_lo((v).w); a7 += bf_hi((v).w); } while (0)

// Load an 8-bf16 MFMA fragment from LDS as 2x ds_read_b64 (8B-aligned, LDA=132)
__device__ __forceinline__ bf16x8 ld_frag8(const ushort16* p) {
    uint2 lo = *(const uint2*)p;
    uint2 hi = *(const uint2*)(p + 4);
    union { uint32 u[4]; bf16x8 v; } x;
    x.u[0] = lo.x; x.u[1] = lo.y; x.u[2] = hi.x; x.u[3] = hi.y;
    return x.v;
}

// ---------------------------------------------------------------------------
// CSR build, all-binned: pass1 fixed-stride bucket scatter ->
// per-bucket degree count (LDS atomics) -> tiny bucket scan ->
// pass2 local scan + fine scatter + pad fill. No global random atomics.
// ---------------------------------------------------------------------------

// Pass 1: bin (src,dst) pairs into fixed-stride coarse buckets (write-combining).
__global__ __launch_bounds__(256) void bin_pass1_kernel(
        const int* __restrict__ ei, int* __restrict__ gcursor,
        uint2* __restrict__ staging) {
    __shared__ int hist[NBKT];
    __shared__ int base[NBKT];
    int tid = threadIdx.x;
    int e0 = blockIdx.x * BIN_CHUNK;

    for (int i = tid; i < NBKT; i += 256) hist[i] = 0;
    __syncthreads();

    #pragma unroll
    for (int k = 0; k < EPT; k++) {
        int e = e0 + k * 256 + tid;
        if (e < NE) {
            int d = ei[NE + e];
            atomicAdd(&hist[d >> BSH], 1);
        }
    }
    __syncthreads();

    for (int i = tid; i < NBKT; i += 256) {
        int c = hist[i];
        base[i] = c ? atomicAdd(&gcursor[i], c) : 0;
        hist[i] = 0;
    }
    __syncthreads();

    #pragma unroll
    for (int k = 0; k < EPT; k++) {
        int e = e0 + k * 256 + tid;
        if (e < NE) {
            int s = ei[e];
            int d = ei[NE + e];
            int b = d >> BSH;
            int off = atomicAdd(&hist[b], 1);
            staging[(size_t)b * CAP + base[b] + off] = make_uint2((uint32)s, (uint32)d);
        }
    }
}

// Per-bucket degree count via LDS atomics; writes deg + dis coalesced and
// the bucket's padded-degree total.
__global__ __launch_bounds__(256) void deg_bucket_kernel(
        const uint2* __restrict__ staging, const int* __restrict__ gcursor,
        int* __restrict__ deg, float* __restrict__ dis, int* __restrict__ bucket_tot) {
    __shared__ int cnt[1 << BSH];
    __shared__ int red[1 << BSH];
    int b = blockIdx.x;
    int node0 = b << BSH;
    int tid = threadIdx.x;
    int n_edges = gcursor[b];

    if (tid < (1 << BSH)) cnt[tid] = 0;
    __syncthreads();

    for (int i = tid; i < n_edges; i += 256) {
        uint2 p = staging[(size_t)b * CAP + i];
        atomicAdd(&cnt[p.y & ((1 << BSH) - 1)], 1);
    }
    __syncthreads();

    if (tid < (1 << BSH)) {
        int node = node0 + tid;
        int c = cnt[tid];
        if (node < NN) {
            deg[node] = c;
            dis[node] = (c > 0) ? rsqrtf((float)c) : 0.0f;
            red[tid] = (c + 7) & ~7;
        } else {
            red[tid] = 0;
        }
    }
    __syncthreads();
    for (int off = (1 << BSH) / 2; off > 0; off >>= 1) {
        if (tid < off) red[tid] += red[tid + off];
        __syncthreads();
    }
    if (tid == 0) bucket_tot[b] = red[0];
}

// Exclusive scan over NBKT bucket totals (single block, 1024 threads).
__global__ void bucket_scan_kernel(const int* __restrict__ bucket_tot,
                                   int* __restrict__ bucket_base,
                                   int* __restrict__ row_start) {
    __shared__ int buf[1024];
    int tid = threadIdx.x;
    int v = (tid < NBKT) ? bucket_tot[tid] : 0;
    buf[tid] = v;
    __syncthreads();
    for (int off = 1; off < 1024; off <<= 1) {
        int t = (tid >= off) ? buf[tid - off] : 0;
        __syncthreads();
        buf[tid] += t;
        __syncthreads();
    }
    if (tid < NBKT) bucket_base[tid] = buf[tid] - v;
    if (tid == NBKT - 1) row_start[NN] = buf[tid];   // total padded edges
}

// Pass 2: per bucket: local 128-wide exclusive scan of padded degrees ->
// row_start; LDS cursors; fine scatter into ssrc; pad fill with dummy NN.
__global__ __launch_bounds__(256) void bin_pass2_kernel(
        const uint2* __restrict__ staging, const int* __restrict__ gcursor,
        const int* __restrict__ deg, const int* __restrict__ bucket_base,
        int* __restrict__ row_start, int* __restrict__ ssrc) {
    __shared__ int sb[1 << BSH];     // scan buffer
    __shared__ int cur[1 << BSH];    // write cursors
    __shared__ int pend[1 << BSH];   // padded end
    int b = blockIdx.x;
    int node0 = b << BSH;
    int tid = threadIdx.x;
    int n_edges = gcursor[b];

    int p = 0;
    if (tid < (1 << BSH)) {
        int node = node0 + tid;
        p = (node < NN) ? ((deg[node] + 7) & ~7) : 0;
        sb[tid] = p;
    }
    __syncthreads();
    #pragma unroll
    for (int off = 1; off < (1 << BSH); off <<= 1) {
        int t = (tid >= off && tid < (1 << BSH)) ? sb[tid - off] : 0;
        __syncthreads();
        if (tid < (1 << BSH)) sb[tid] += t;
        __syncthreads();
    }
    if (tid < (1 << BSH)) {
        int rs = bucket_base[b] + sb[tid] - p;   // exclusive
        cur[tid] = rs;
        pend[tid] = rs + p;
        int node = node0 + tid;
        if (node < NN) row_start[node] = rs;
    }
    __syncthreads();

    for (int i = tid; i < n_edges; i += 256) {
        uint2 pr = staging[(size_t)b * CAP + i];
        int off = atomicAdd(&cur[pr.y & ((1 << BSH) - 1)], 1);
        ssrc[off] = (int)pr.x;
    }
    __syncthreads();

    if (tid < (1 << BSH)) {
        int node = node0 + tid;
        if (node < NN) {
            for (int q = cur[tid]; q < pend[tid]; q++) ssrc[q] = NN;   // dummy -> zero row
        }
    }
}

// ---------------------------------------------------------------------------
// MFMA bf16 GEMM: out[M,N] = bf16( (A[M,128] @ W[128,N]) * dis[row] )
// BM=64, full K=128 resident in LDS, one barrier per block.
// ---------------------------------------------------------------------------
template <int N, bool ABF16>
__global__ __launch_bounds__(256) void gemm_mfma_kernel(
        const void* __restrict__ Ap, const float* __restrict__ W,
        const float* __restrict__ dis, ushort16* __restrict__ out, int M) {
    constexpr int BM = 64, K = K_DIM;
    constexpr int LDA = 132;
    constexpr int NT = N / 16;
    constexpr int NLOG = (N == 128) ? 7 : 6;

    __shared__ ushort16 As[BM * LDA];
    __shared__ ushort16 Bt[N * LDA];

    int tid = threadIdx.x;
    int row0 = blockIdx.x * BM;

    if constexpr (!ABF16) {
        const float* A = (const float*)Ap;
        #pragma unroll
        for (int c = 0; c < 8; c++) {
            int idx = c * 1024 + tid * 4;
            int r = idx >> 7, col = idx & 127;
            int ra = row0 + r;
            float4 v = (ra < M) ? *(const float4*)&A[(size_t)ra * K + col]
                                : make_float4(0.f, 0.f, 0.f, 0.f);
            ushort4 bq;
            bq.x = f2bf(v.x); bq.y = f2bf(v.y); bq.z = f2bf(v.z); bq.w = f2bf(v.w);
            *(ushort4*)&As[r * LDA + col] = bq;
        }
    } else {
        const ushort16* A = (const ushort16*)Ap;
        #pragma unroll
        for (int c = 0; c < 4; c++) {
            int idx = c * 2048 + tid * 8;
            int r = idx >> 7, col = idx & 127;
            int ra = row0 + r;
            uint4 v = make_uint4(0u, 0u, 0u, 0u);
            if (ra < M) v = *(const uint4*)&A[(size_t)ra * K + col];
            *(uint2*)&As[r * LDA + col]     = make_uint2(v.x, v.y);
            *(uint2*)&As[r * LDA + col + 4] = make_uint2(v.z, v.w);
        }
    }
    {
        #pragma unroll
        for (int c = 0; c < (K * N) / 1024; c++) {
            int idx = c * 1024 + tid * 4;
            int k = idx >> NLOG, n = idx & (N - 1);
            float4 v = *(const float4*)&W[idx];
            Bt[(n + 0) * LDA + k] = f2bf(v.x);
            Bt[(n + 1) * LDA + k] = f2bf(v.y);
            Bt[(n + 2) * LDA + k] = f2bf(v.z);
            Bt[(n + 3) * LDA + k] = f2bf(v.w);
        }
    }
    __syncthreads();

    int lane = tid & 63;
    int wv = tid >> 6;
    int m0 = wv * 16;
    int ml = lane & 15;
    int quad = lane >> 4;

    f32x4 acc[NT];
    #pragma unroll
    for (int i = 0; i < NT; i++) acc[i] = (f32x4){0.f, 0.f, 0.f, 0.f};

    #pragma unroll
    for (int ks = 0; ks < 4; ks++) {
        int kof = ks * 32 + quad * 8;
        bf16x8 a = ld_frag8(&As[(m0 + ml) * LDA + kof]);
        #pragma unroll
        for (int nt = 0; nt < NT; nt++) {
            bf16x8 bb = ld_frag8(&Bt[(nt * 16 + ml) * LDA + kof]);
            acc[nt] = __builtin_amdgcn_mfma_f32_16x16x32_bf16(a, bb, acc[nt], 0, 0, 0);
        }
    }

    #pragma unroll
    for (int r = 0; r < 4; r++) {
        int row = row0 + m0 + quad * 4 + r;
        if (row < M) {
            float s = dis[row];
            #pragma unroll
            for (int nt = 0; nt < NT; nt++)
                out[(size_t)row * N + nt * 16 + ml] = f2bf(acc[nt][r] * s);
        }
    }
}

// ---------------------------------------------------------------------------
// Aggregation layer 1: F=128, bf16 gather -> bf16 out with ReLU.
// One wave per node. Preload up to 64 edge indices in one ssrc load
// (removes the per-batch ssrc-load from the dependency chain), then
// 2-batch unrolled gather: 4 dwordx4 loads (4 KB) in flight per step.
// Lane covers feats (lane&15)*8..+7; quad (lane>>4) is the edge sub-slot.
// ---------------------------------------------------------------------------
__global__ __launch_bounds__(256) void agg128_kernel(
        const ushort16* __restrict__ g, const int* __restrict__ row_start,
        const int* __restrict__ ssrc, const float* __restrict__ dis,
        const float* __restrict__ bias, ushort16* __restrict__ out) {
    int wave = (blockIdx.x * 256 + threadIdx.x) >> 6;
    int lane = threadIdx.x & 63;
    if (wave >= NN) return;

    int beg = row_start[wave];
    int end = row_start[wave + 1];
    int ecount = end - beg;
    float sc = dis[wave];

    int fl = lane & 15;            // feature octet: feats fl*8..fl*8+7
    int q  = lane >> 4;            // edge sub-slot 0..3
    int laneoff = fl * 16;         // byte offset within a 256B row

    // Preload 64 indices. Memory-safe: total padded edges + 64 < PADE.
    // Lanes >= ecount hold garbage but are never shfl-sourced.
    int idx = ssrc[beg + lane];

    float a0 = 0.f, a1 = 0.f, a2 = 0.f, a3 = 0.f;
    float a4 = 0.f, a5 = 0.f, a6 = 0.f, a7 = 0.f;

    const char* gb = (const char*)g;
    int nb = ((ecount < 64) ? ecount : 64) >> 3;   // batches covered by preload
    int b = 0;
    for (; b + 2 <= nb; b += 2) {
        int s0a = __shfl(idx, b * 8 + q);
        int s1a = __shfl(idx, b * 8 + 4 + q);
        int s0b = __shfl(idx, b * 8 + 8 + q);
        int s1b = __shfl(idx, b * 8 + 12 + q);
        uint4 v0a = *(const uint4*)(gb + (((uint32)s0a << 8) + laneoff));
        uint4 v1a = *(const uint4*)(gb + (((uint32)s1a << 8) + laneoff));
        uint4 v0b = *(const uint4*)(gb + (((uint32)s0b << 8) + laneoff));
        uint4 v1b = *(const uint4*)(gb + (((uint32)s1b << 8) + laneoff));
        ACC8(v0a); ACC8(v1a); ACC8(v0b); ACC8(v1b);
    }
    if (b < nb) {
        int s0 = __shfl(idx, b * 8 + q);
        int s1 = __shfl(idx, b * 8 + 4 + q);
        uint4 v0 = *(const uint4*)(gb + (((uint32)s0 << 8) + laneoff));
        uint4 v1 = *(const uint4*)(gb + (((uint32)s1 << 8) + laneoff));
        ACC8(v0); ACC8(v1);
    }
    // Rare tail: rows with more than 64 edges.
    for (int e = beg + 64; e < end; e += 8) {
        int idx2 = ssrc[e + (lane & 7)];
        int s0 = __shfl(idx2, q);
        int s1 = __shfl(idx2, 4 + q);
        uint4 v0 = *(const uint4*)(gb + (((uint32)s0 << 8) + laneoff));
        uint4 v1 = *(const uint4*)(gb + (((uint32)s1 << 8) + laneoff));
        ACC8(v0); ACC8(v1);
    }

    // combine the 4 quad partial sums (tree)
    a0 += __shfl_xor(a0, 16); a1 += __shfl_xor(a1, 16);
    a2 += __shfl_xor(a2, 16); a3 += __shfl_xor(a3, 16);
    a4 += __shfl_xor(a4, 16); a5 += __shfl_xor(a5, 16);
    a6 += __shfl_xor(a6, 16); a7 += __shfl_xor(a7, 16);
    a0 += __shfl_xor(a0, 32); a1 += __shfl_xor(a1, 32);
    a2 += __shfl_xor(a2, 32); a3 += __shfl_xor(a3, 32);
    a4 += __shfl_xor(a4, 32); a5 += __shfl_xor(a5, 32);
    a6 += __shfl_xor(a6, 32); a7 += __shfl_xor(a7, 32);

    if (lane < 16) {
        float4 bA = *(const float4*)&bias[fl * 8];
        float4 bB = *(const float4*)&bias[fl * 8 + 4];
        float o0 = fmaxf(sc * a0 + bA.x, 0.f);
        float o1 = fmaxf(sc * a1 + bA.y, 0.f);
        float o2 = fmaxf(sc * a2 + bA.z, 0.f);
        float o3 = fmaxf(sc * a3 + bA.w, 0.f);
        float o4 = fmaxf(sc * a4 + bB.x, 0.f);
        float o5 = fmaxf(sc * a5 + bB.y, 0.f);
        float o6 = fmaxf(sc * a6 + bB.z, 0.f);
        float o7 = fmaxf(sc * a7 + bB.w, 0.f);
        uint4 pk;
        pk.x = ((uint32)f2bf(o1) << 16) | (uint32)f2bf(o0);
        pk.y = ((uint32)f2bf(o3) << 16) | (uint32)f2bf(o2);
        pk.z = ((uint32)f2bf(o5) << 16) | (uint32)f2bf(o4);
        pk.w = ((uint32)f2bf(o7) << 16) | (uint32)f2bf(o6);
        *(uint4*)&out[(size_t)wave * 128 + fl * 8] = pk;
    }
}

// ---------------------------------------------------------------------------
// Aggregation layer 2: F=64, bf16 gather -> f32 out (no activation).
// Half-wave per node. Preload up to 32 indices per half in one ssrc load,
// then 2-batch unrolled gather (4 dwordx4 loads in flight).
// Lane covers feats (l2&7)*8..+7; group (l2>>3) is the edge sub-slot.
// ---------------------------------------------------------------------------
__global__ __launch_bounds__(256) void agg64_kernel(
        const ushort16* __restrict__ g, const int* __restrict__ row_start,
        const int* __restrict__ ssrc, const float* __restrict__ dis,
        const float* __restrict__ bias, float* __restrict__ out) {
    int wave = (blockIdx.x * 256 + threadIdx.x) >> 6;
    int lane = threadIdx.x & 63;
    int half = lane >> 5;
    int l2 = lane & 31;
    int node = wave * 2 + half;          // NN even => both halves valid
    if (node >= NN) return;

    int beg = row_start[node];
    int end = row_start[node + 1];
    int ecount = end - beg;
    float sc = dis[node];

    int fl = l2 & 7;               // feature octet: feats fl*8..fl*8+7
    int q  = l2 >> 3;              // edge sub-slot 0..3
    int laneoff = fl * 16;         // byte offset within a 128B row

    // Preload 32 indices per half (memory-safe: PADE slack).
    int idx = ssrc[beg + l2];

    float a0 = 0.f, a1 = 0.f, a2 = 0.f, a3 = 0.f;
    float a4 = 0.f, a5 = 0.f, a6 = 0.f, a7 = 0.f;

    const char* gb = (const char*)g;
    int nb = ((ecount < 32) ? ecount : 32) >> 3;
    int b = 0;
    for (; b + 2 <= nb; b += 2) {
        int s0a = __shfl(idx, half * 32 + b * 8 + q);
        int s1a = __shfl(idx, half * 32 + b * 8 + 4 + q);
        int s0b = __shfl(idx, half * 32 + b * 8 + 8 + q);
        int s1b = __shfl(idx, half * 32 + b * 8 + 12 + q);
        uint4 v0a = *(const uint4*)(gb + (((uint32)s0a << 7) + laneoff));
        uint4 v1a = *(const uint4*)(gb + (((uint32)s1a << 7) + laneoff));
        uint4 v0b = *(const uint4*)(gb + (((uint32)s0b << 7) + laneoff));
        uint4 v1b = *(const uint4*)(gb + (((uint32)s1b << 7) + laneoff));
        ACC8(v0a); ACC8(v1a); ACC8(v0b); ACC8(v1b);
    }
    if (b < nb) {
        int s0 = __shfl(idx, half * 32 + b * 8 + q);
        int s1 = __shfl(idx, half * 32 + b * 8 + 4 + q);
        uint4 v0 = *(const uint4*)(gb + (((uint32)s0 << 7) + laneoff));
        uint4 v1 = *(const uint4*)(gb + (((uint32)s1 << 7) + laneoff));
        ACC8(v0); ACC8(v1);
    }
    // Rare tail: rows with more than 32 edges (per half; divergent-safe).
    for (int e = beg + 32; e < end; e += 8) {
        int idx2 = ssrc[e + (l2 & 7)];
        int s0 = __shfl(idx2, half * 32 + q);
        int s1 = __shfl(idx2, half * 32 + 4 + q);
        uint4 v0 = *(const uint4*)(gb + (((uint32)s0 << 7) + laneoff));
        uint4 v1 = *(const uint4*)(gb + (((uint32)s1 << 7) + laneoff));
        ACC8(v0); ACC8(v1);
    }

    // combine the 4 sub-slot partial sums (tree), within each half-wave
    a0 += __shfl_xor(a0, 8);  a1 += __shfl_xor(a1, 8);
    a2 += __shfl_xor(a2, 8);  a3 += __shfl_xor(a3, 8);
    a4 += __shfl_xor(a4, 8);  a5 += __shfl_xor(a5, 8);
    a6 += __shfl_xor(a6, 8);  a7 += __shfl_xor(a7, 8);
    a0 += __shfl_xor(a0, 16); a1 += __shfl_xor(a1, 16);
    a2 += __shfl_xor(a2, 16); a3 += __shfl_xor(a3, 16);
    a4 += __shfl_xor(a4, 16); a5 += __shfl_xor(a5, 16);
    a6 += __shfl_xor(a6, 16); a7 += __shfl_xor(a7, 16);

    if (l2 < 8) {
        float4 bA = *(const float4*)&bias[fl * 8];
        float4 bB = *(const float4*)&bias[fl * 8 + 4];
        float4 oA = make_float4(sc * a0 + bA.x, sc * a1 + bA.y,
                                sc * a2 + bA.z, sc * a3 + bA.w);
        float4 oB = make_float4(sc * a4 + bB.x, sc * a5 + bB.y,
                                sc * a6 + bB.z, sc * a7 + bB.w);
        *(float4*)&out[(size_t)node * 64 + fl * 8]     = oA;
        *(float4*)&out[(size_t)node * 64 + fl * 8 + 4] = oB;
    }
}

// ---------------------------------------------------------------------------
// Launch
// ---------------------------------------------------------------------------
extern "C" void kernel_launch(void* const* d_in, const int* in_sizes, int n_in,
                              void* d_out, int out_size, void* d_ws, size_t ws_size,
                              hipStream_t stream) {
    const float* x  = (const float*)d_in[0];
    const int*   ei = (const int*)d_in[1];
    const float* W1 = (const float*)d_in[2];
    const float* b1 = (const float*)d_in[3];
    const float* W2 = (const float*)d_in[4];
    const float* b2 = (const float*)d_in[5];
    float* out = (float*)d_out;

    char* ws = (char*)d_ws;
    size_t off = 0;
    auto alloc = [&](size_t bytes) {
        void* p = ws + off;
        off = (off + bytes + 255) & ~(size_t)255;
        return p;
    };

    int*      deg_i      = (int*)alloc(NN * 4);
    float*    dis        = (float*)alloc(NN * 4);
    int*      row_start  = (int*)alloc((NN + 1) * 4);
    int*      gcursor    = (int*)alloc(NBKT * 4);
    int*      bucket_tot = (int*)alloc(NBKT * 4);
    int*      bucket_bse = (int*)alloc(NBKT * 4);
    int*      ssrc       = (int*)alloc((size_t)PADE * 4);
    ushort16* g1         = (ushort16*)alloc((size_t)(NN + 1) * 128 * 2);  // +zero row
    // staging (25.62 MB) and h (25.6 MB) share one region: staging is dead
    // after bin_pass2 (before gemm128), h written first by agg128.
    char*     big        = (char*)alloc((size_t)NBKT * CAP * 8);
    uint2*    staging    = (uint2*)big;
    ushort16* h          = (ushort16*)big;
    ushort16* g2         = g1;               // alias: g1 dead after agg1

    hipMemsetAsync(gcursor, 0, NBKT * 4, stream);
    hipMemsetAsync((char*)g1 + (size_t)NN * 256, 0, 256, stream);   // g1 zero row

    bin_pass1_kernel<<<(NE + BIN_CHUNK - 1) / BIN_CHUNK, 256, 0, stream>>>(ei, gcursor, staging);
    deg_bucket_kernel<<<NBKT, 256, 0, stream>>>(staging, gcursor, deg_i, dis, bucket_tot);
    bucket_scan_kernel<<<1, 1024, 0, stream>>>(bucket_tot, bucket_bse, row_start);
    bin_pass2_kernel<<<NBKT, 256, 0, stream>>>(staging, gcursor, deg_i, bucket_bse, row_start, ssrc);

    const int GEMM_BLOCKS = (NN + 63) / 64;   // 1563
    gemm_mfma_kernel<128, false><<<GEMM_BLOCKS, 256, 0, stream>>>(x, W1, dis, g1, NN);

    const int AGG_BLOCKS = (NN + 3) / 4;      // 25000 (4 waves/block)
    agg128_kernel<<<AGG_BLOCKS, 256, 0, stream>>>(g1, row_start, ssrc, dis, b1, h);

    hipMemsetAsync((char*)g2 + (size_t)NN * 128, 0, 128, stream);   // g2 zero row (g1 now dead)

    gemm_mfma_kernel<64, true><<<GEMM_BLOCKS, 256, 0, stream>>>(h, W2, dis, g2, NN);

    const int AGG2_BLOCKS = (NN / 2 + 3) / 4; // 12500 (half-wave per node)
    agg64_kernel<<<AGG2_BLOCKS, 256, 0, stream>>>(g2, row_start, ssrc, dis, b2, out);
}